// Round 14
// baseline (276.177 us; speedup 1.0000x reference)
//
#include <hip/hip_runtime.h>
#include <hip/hip_bf16.h>
#include <cstdint>

// ---------------------------------------------------------------------------
// MoE CNN, hard top-1 dispatch. Round 14:
//  - conv2: R7 partition (64 couts x 32 spatial/wave, 1 B-ds_read per 2 MFMA)
//    now that A loads are lane-contiguous (R10 wp layout). ds_reads halved.
//  - conv1: expert weights staged in LDS (kills s_load lgkmcnt stall chains).
// Sizes: B=1024, Cin=3, HW=32, GC=16, E=4, C1=64, C2=128, FC_IN=8192, NC=100
// Output: [final 1024*100][probs 1024*4][aux 1]
// ---------------------------------------------------------------------------

#define B_TOT 1024

typedef __attribute__((ext_vector_type(8))) short short8;
typedef __attribute__((ext_vector_type(16))) float f32x16;

__device__ __forceinline__ ushort f2bf(float f) {
  uint32_t u = __float_as_uint(f);
  u += 0x7fffu + ((u >> 16) & 1u);  // round-to-nearest-even
  return (ushort)(u >> 16);
}

// ------- K0: w2 fp32 [e][cout][ci][3][3] -> bf16 [e][kk][kb 8][cout 128][8] -
__global__ __launch_bounds__(256) void k_wprep(const float* __restrict__ w2,
                                               ushort* __restrict__ wp) {
  const int i = blockIdx.x * 256 + threadIdx.x;  // 294912 total
  const int j = i & 7;
  const int cout = (i >> 3) & 127;
  const int kb = (i >> 10) & 7;
  const int kkE = i >> 13;          // e*9 + kk
  const int kk = kkE - (kkE / 9) * 9;
  const int e = kkE / 9;
  const int ci = kb * 8 + j;
  const float f = w2[(size_t)(((e * 128 + cout) * 64 + ci) * 9) + kk];
  wp[i] = f2bf(f);
}

// ---------------- K0b: efw fp32 [e][100][8192] -> bf16 [e][kb][cout128][8] -
__global__ __launch_bounds__(256) void k_wfc(const float* __restrict__ efw,
                                             ushort* __restrict__ wfc) {
  const int i = blockIdx.x * 256 + threadIdx.x;  // 4194304 total
  const int j = i & 7;
  const int cout = (i >> 3) & 127;
  const int kb = (i >> 10) & 1023;
  const int e = i >> 20;
  const int k = kb * 8 + j;
  float f = 0.f;
  if (cout < 100) f = efw[((size_t)(e * 100 + cout)) * 8192 + k];
  wfc[i] = f2bf(f);
}

// ---------------- K1: gate conv(3->16)+relu+gap, LDS halo, maskless --------
__global__ __launch_bounds__(256, 2) void k_gate(
    const float* __restrict__ x, const float* __restrict__ gcw,
    const float* __restrict__ gcb, float* __restrict__ g_mean) {
  __shared__ float xs[3 * 34 * 34];  // 13872 B zero-padded halo
  __shared__ float red[4 * 16];
  const int b = blockIdx.x;
  const int t = threadIdx.x;
  const float* xb = x + (size_t)b * 3072;

  for (int c = t; c < 3468; c += 256) {
    const int ci = c / 1156;
    const int rem = c - ci * 1156;
    const int y = rem / 34;
    const int xx = rem - y * 34;
    const int gy = y - 1, gx = xx - 1;
    float v = 0.f;
    if (gy >= 0 && gy < 32 && gx >= 0 && gx < 32) v = xb[ci * 1024 + gy * 32 + gx];
    xs[c] = v;
  }
  __syncthreads();

  const int r = t >> 3;        // output row 0..31
  const int c0 = (t & 7) * 4;  // output col base

  float accp[16][4];
#pragma unroll
  for (int c = 0; c < 16; c++)
#pragma unroll
    for (int p = 0; p < 4; p++) accp[c][p] = 0.f;

#pragma unroll
  for (int ci = 0; ci < 3; ci++) {
    float pv[3][6];
#pragma unroll
    for (int dy = 0; dy < 3; dy++) {
      const float* row = xs + ci * 1156 + (r + dy) * 34 + c0;
#pragma unroll
      for (int dx = 0; dx < 6; dx++) pv[dy][dx] = row[dx];
    }
#pragma unroll
    for (int c = 0; c < 16; c++) {
      const float* wr = gcw + (c * 3 + ci) * 9;
#pragma unroll
      for (int ky = 0; ky < 3; ky++)
#pragma unroll
        for (int kx = 0; kx < 3; kx++) {
          const float wv = wr[ky * 3 + kx];
#pragma unroll
          for (int p = 0; p < 4; p++)
            accp[c][p] += wv * pv[ky][kx + p];
        }
    }
  }

  float sums[16];
#pragma unroll
  for (int c = 0; c < 16; c++) {
    const float bb = gcb[c];
    float s = 0.f;
#pragma unroll
    for (int p = 0; p < 4; p++) s += fmaxf(accp[c][p] + bb, 0.f);
    sums[c] = s;
  }

  const int wave = t >> 6, lane = t & 63;
#pragma unroll
  for (int c = 0; c < 16; c++) {
    float v = sums[c];
    for (int o = 32; o > 0; o >>= 1) v += __shfl_down(v, o);
    if (lane == 0) red[wave * 16 + c] = v;
  }
  __syncthreads();
  if (t < 16) {
    g_mean[b * 16 + t] =
        (red[t] + red[16 + t] + red[32 + t] + red[48 + t]) * (1.f / 1024.f);
  }
}

// ---------------- K2: router linear+softmax, argmax, counts ----------------
__global__ __launch_bounds__(256) void k_router(
    const float* __restrict__ g_mean, const float* __restrict__ gfw,
    const float* __restrict__ gfb, float* __restrict__ probs,
    float* __restrict__ best_w, int* __restrict__ best_idx,
    int* __restrict__ counts) {
  const int b = blockIdx.x * 256 + threadIdx.x;
  float g[16];
#pragma unroll
  for (int c = 0; c < 16; c++) g[c] = g_mean[b * 16 + c];
  float lg[4];
#pragma unroll
  for (int e = 0; e < 4; e++) {
    float s = gfb[e];
#pragma unroll
    for (int c = 0; c < 16; c++) s += g[c] * gfw[e * 16 + c];
    lg[e] = s;
  }
  float m = fmaxf(fmaxf(lg[0], lg[1]), fmaxf(lg[2], lg[3]));
  float ex[4], s = 0.f;
#pragma unroll
  for (int e = 0; e < 4; e++) { ex[e] = expf(lg[e] - m); s += ex[e]; }
  const float inv = 1.f / s;
  float p[4];
#pragma unroll
  for (int e = 0; e < 4; e++) { p[e] = ex[e] * inv; probs[b * 4 + e] = p[e]; }
  int bi = 0; float bp = p[0];
#pragma unroll
  for (int e = 1; e < 4; e++) if (p[e] > bp) { bp = p[e]; bi = e; }
  best_w[b] = bp;
  best_idx[b] = bi;
  atomicAdd(&counts[bi], 1);
}

// ---------------- K2c: 32-aligned segment offsets --------------------------
__global__ void k_offsets(const int* __restrict__ counts, int* __restrict__ off) {
  if (threadIdx.x == 0) {
    int o = 0;
    for (int e = 0; e < 4; e++) { off[e] = o; o += ((counts[e] + 31) & ~31); }
    off[4] = o;
  }
}

// ---------------- K2d: scatter sample ids grouped by expert ----------------
__global__ __launch_bounds__(256) void k_scatter(
    const int* __restrict__ best_idx, const int* __restrict__ off,
    int* __restrict__ cnt2, int* __restrict__ order) {
  const int b = blockIdx.x * 256 + threadIdx.x;
  const int e = best_idx[b];
  const int slot = off[e] + atomicAdd(&cnt2[e], 1);
  order[slot] = b;
}

// ---------------- K3: aux loss ---------------------------------------------
__global__ __launch_bounds__(256) void k_aux(const float* __restrict__ probs,
                                             float* __restrict__ aux_out) {
  __shared__ float red[16];
  const int t = threadIdx.x;
  const int wave = t >> 6, lane = t & 63;
  float sums[4] = {0.f, 0.f, 0.f, 0.f};
  for (int b = t; b < B_TOT; b += 256) {
#pragma unroll
    for (int e = 0; e < 4; e++) sums[e] += probs[b * 4 + e];
  }
#pragma unroll
  for (int e = 0; e < 4; e++) {
    float v = sums[e];
    for (int o = 32; o > 0; o >>= 1) v += __shfl_down(v, o);
    if (lane == 0) red[wave * 4 + e] = v;
  }
  __syncthreads();
  if (t == 0) {
    float aux = 0.f;
#pragma unroll
    for (int e = 0; e < 4; e++) {
      const float mp = (red[e] + red[4 + e] + red[8 + e] + red[12 + e]) * (1.f / 1024.f);
      const float d = mp - 0.25f;
      aux += d * d;
    }
    aux_out[0] = aux * 0.25f;
  }
}

// ---------------- K4: conv1(3->64)+relu+pool, LDS halo + LDS weights -------
// h1 layout: [b][cig 8][pos 256][8] -> lane-contiguous coalesced stores.
__global__ __launch_bounds__(256, 2) void k_conv1(
    const float* __restrict__ x, const float* __restrict__ w1,
    const float* __restrict__ b1, const int* __restrict__ best_idx,
    ushort* __restrict__ h1q) {
  __shared__ float xs[3 * 34 * 34];  // zero-padded halo
  __shared__ float wls[1728];        // expert conv1 weights (broadcast reads)
  const int b = blockIdx.x;
  const int t = threadIdx.x;
  const int e = __builtin_amdgcn_readfirstlane(best_idx[b]);
  const float* xb = x + (size_t)b * 3072;
  const float* w1e = w1 + (size_t)e * 1728;
  const float* b1e = b1 + (size_t)e * 64;

  for (int c = t; c < 3468; c += 256) {
    const int ci = c / 1156;
    const int rem = c - ci * 1156;
    const int y = rem / 34;
    const int xx = rem - y * 34;
    const int gy = y - 1, gx = xx - 1;
    float v = 0.f;
    if (gy >= 0 && gy < 32 && gx >= 0 && gx < 32) v = xb[ci * 1024 + gy * 32 + gx];
    xs[c] = v;
  }
  for (int c = t; c < 1728; c += 256) wls[c] = w1e[c];
  __syncthreads();

  const int py = t >> 4, px = t & 15;
  float pv[3][4][4];
#pragma unroll
  for (int ci = 0; ci < 3; ci++)
#pragma unroll
    for (int i = 0; i < 4; i++) {
      const float* row = xs + ci * 1156 + (2 * py + i) * 34 + 2 * px;
#pragma unroll
      for (int j = 0; j < 4; j++) pv[ci][i][j] = row[j];
    }

  ushort* h1b = h1q + (size_t)b * 16384 + t * 8;  // + cig*2048
#pragma unroll
  for (int g = 0; g < 8; g++) {
    float acc[8][4];
#pragma unroll
    for (int m = 0; m < 8; m++)
#pragma unroll
      for (int q = 0; q < 4; q++) acc[m][q] = 0.f;
#pragma unroll
    for (int m = 0; m < 8; m++) {
      const float* wr = wls + (g * 8 + m) * 27;
#pragma unroll
      for (int ci = 0; ci < 3; ci++)
#pragma unroll
        for (int ky = 0; ky < 3; ky++)
#pragma unroll
          for (int kx = 0; kx < 3; kx++) {
            const float wv = wr[ci * 9 + ky * 3 + kx];
#pragma unroll
            for (int dy = 0; dy < 2; dy++)
#pragma unroll
              for (int dx = 0; dx < 2; dx++)
                acc[m][dy * 2 + dx] += wv * pv[ci][ky + dy][kx + dx];
          }
    }
    union { ushort us[8]; uint4 u4; } pk;
#pragma unroll
    for (int m = 0; m < 8; m++) {
      float v = fmaxf(fmaxf(acc[m][0], acc[m][1]), fmaxf(acc[m][2], acc[m][3]));
      pk.us[m] = f2bf(fmaxf(v + b1e[g * 8 + m], 0.f));
    }
    *(uint4*)(h1b + g * 2048) = pk.u4;
  }
}

// ---------------- K4b: conv2 bf16 MFMA, 64 couts x 32 spatial per wave -----
// Wave wv: cout group (wv&1)*64, strip-half h=wv>>1 (pre-pool rows 2h,2h+1).
// Per (kk,c4): 2 lane-contiguous A loads + 1 B ds_read -> 2 MFMA.
__global__ __launch_bounds__(256) void k_conv2(
    const ushort* __restrict__ h1q, const ushort* __restrict__ wp,
    const float* __restrict__ b2, const int* __restrict__ best_idx,
    ushort* __restrict__ h2q) {
  __shared__ uint4 st[864];   // [row 6][cig 8][col 18] x 16B (8 ci bf16)
  __shared__ float pl[2048];  // [cout 128][pooled 16]
  const int blk = blockIdx.x;
  const int b = blk >> 2;
  const int yq = blk & 3;  // out rows yq*4 .. yq*4+3
  const int t = threadIdx.x;
  const int e = __builtin_amdgcn_readfirstlane(best_idx[b]);

  // stage h1 rows yq*4-1 .. yq*4+4 (zero-padded) into LDS
  for (int c = t; c < 864; c += 256) {
    const int row = c / 144;           // 8*18
    const int rem = c - row * 144;
    const int cig = rem / 18;
    const int col = rem - cig * 18;
    const int gy = yq * 4 - 1 + row;
    uint4 v = make_uint4(0u, 0u, 0u, 0u);
    if (gy >= 0 && gy < 16 && col >= 1 && col <= 16)
      v = *(const uint4*)(h1q + (size_t)b * 16384 + cig * 2048 +
                          (gy * 16 + col - 1) * 8);
    st[c] = v;  // c == (row*8+cig)*18+col
  }
  __syncthreads();

  const int wv = t >> 6;
  const int g = wv & 1;       // cout group: g*64
  const int h = wv >> 1;      // strip half: pre-pool rows 2h, 2h+1
  const int lane = t & 63;
  const int n = lane & 31;
  const int half = lane >> 5; // k-half
  const int drow = n >> 4;
  const int col = n & 15;
  const int cm0 = g * 64;

  f32x16 acc0, acc1;
#pragma unroll
  for (int i = 0; i < 16; i++) { acc0[i] = 0.f; acc1[i] = 0.f; }

  const ushort* wpe = wp + (size_t)e * 73728;
  const short* sb = (const short*)st;

  for (int kk = 0; kk < 9; kk++) {
    const int ky = kk / 3;
    const int kx = kk - ky * 3;
#pragma unroll
    for (int c4 = 0; c4 < 4; c4++) {
      const int cig = c4 * 2 + half;  // = kb
      const short8 af0 = *(const short8*)(wpe + kk * 8192 +
                                          (size_t)(cig * 128 + cm0 + n) * 8);
      const short8 af1 = *(const short8*)(wpe + kk * 8192 +
                                          (size_t)(cig * 128 + cm0 + 32 + n) * 8);
      const short8 bf = *(const short8*)(sb +
          (((2 * h + drow + ky) * 8 + cig) * 18 + col + kx) * 8);
      acc0 = __builtin_amdgcn_mfma_f32_32x32x16_bf16(af0, bf, acc0, 0, 0, 0);
      acc1 = __builtin_amdgcn_mfma_f32_32x32x16_bf16(af1, bf, acc1, 0, 0, 0);
    }
  }

  // fused 2x2 maxpool: cols via shfl_xor(1), rows via shfl_xor(16)
#pragma unroll
  for (int s = 0; s < 2; s++) {
    const f32x16 a = s ? acc1 : acc0;
#pragma unroll
    for (int r = 0; r < 16; r++) {
      float v = a[r];
      v = fmaxf(v, __shfl_xor(v, 1));
      v = fmaxf(v, __shfl_xor(v, 16));
      if ((lane & 17) == 0) {  // col even, drow==0
        const int rowm = (r & 3) + 8 * (r >> 2) + 4 * half;
        const int pc = (n >> 1) & 7;  // pooled col 0..7
        pl[(cm0 + s * 32 + rowm) * 16 + h * 8 + pc] = v;
      }
    }
  }
  __syncthreads();

  // bias + relu + bf16 pack + coalesced write: h2[b][cout][yq*16 + p]
  {
    const int coutL = t >> 1;
    const int hh = t & 1;
    const float bias = b2[e * 128 + coutL];
    const float* src = pl + coutL * 16 + hh * 8;
    union { ushort us[8]; uint4 u4; } pk;
#pragma unroll
    for (int j = 0; j < 8; j++) pk.us[j] = f2bf(fmaxf(src[j] + bias, 0.f));
    *(uint4*)(h2q + (size_t)b * 8192 + coutL * 64 + yq * 16 + hh * 8) = pk.u4;
  }
}

// ---------------- K5: FC bf16 MFMA, split-K=16, partial stores (no atomics) -
// partial layout: [ks 16][cout 128][slot 1152] -> half-wave-contiguous stores
__global__ __launch_bounds__(256) void k_fc(
    const ushort* __restrict__ h2q, const ushort* __restrict__ wfc,
    const int* __restrict__ order, const int* __restrict__ off,
    const int* __restrict__ counts, float* __restrict__ partial) {
  __shared__ ushort bs[32 * 32 * 8];  // 16 KB
  __shared__ int sid[32];
  const int tix = blockIdx.x;
  const int ks = blockIdx.y;  // K-slice of 512
  const int base = tix * 32;
  if (base >= off[4]) return;
  int e = 0;
#pragma unroll
  for (int i = 1; i < 4; i++) if (base >= off[i]) e = i;
  const int vend = off[e] + counts[e];
  const int t = threadIdx.x;
  if (t < 32) {
    const int pos = base + t;
    sid[t] = (pos < vend) ? order[pos] : -1;
  }
  __syncthreads();

  const int lane = t & 63;
  const int wv = t >> 6;
  const int half = lane >> 5;
  const int mn = lane & 31;
  const int cout0 = wv * 32;
  const int ss = t & 31;        // staging sample
  const int kgrp = t >> 5;      // staging kb sub-index 0..7
  const int srow = sid[ss] >= 0 ? sid[ss] : 0;  // safe row
  const ushort* arow = h2q + (size_t)srow * 8192;

  f32x16 acc;
#pragma unroll
  for (int i = 0; i < 16; i++) acc[i] = 0.f;

  const ushort* wbase = wfc + ((size_t)e * 1024 + (size_t)ks * 64) * 1024;  // [kb][128][8]
  const short* sb = (const short*)bs;

#pragma unroll
  for (int ch = 0; ch < 2; ch++) {
    const int k0g = ks * 512 + ch * 256;
    if (ch) __syncthreads();
#pragma unroll
    for (int p = 0; p < 4; p++) {
      const int kb = p * 8 + kgrp;
      const uint4 v = *(const uint4*)(arow + k0g + kb * 8);
      *(uint4*)(bs + (kb * 32 + ss) * 8) = v;
    }
    __syncthreads();
#pragma unroll
    for (int kk = 0; kk < 16; kk++) {
      const int kbl = kk * 2 + half;          // kb within chunk
      const short8 af = *(const short8*)(wbase +
          ((size_t)(ch * 32 + kbl) * 128 + cout0 + mn) * 8);
      const short8 bf = *(const short8*)(sb + (kbl * 32 + mn) * 8);
      acc = __builtin_amdgcn_mfma_f32_32x32x16_bf16(af, bf, acc, 0, 0, 0);
    }
  }

  // store raw partials: C col = mn = slot-base, row -> cout
  float* pks = partial + (size_t)ks * 147456;  // 128*1152
#pragma unroll
  for (int r = 0; r < 16; r++) {
    const int cout = cout0 + (r & 3) + 8 * (r >> 2) + 4 * half;
    pks[(size_t)cout * 1152 + base + mn] = acc[r];
  }
}

// ---------------- K5b: reduce 16 K-slices, +bias, *best_w, write out ------
// grid (5, 25): x -> 256 slots each, y -> 4 couts each.
__global__ __launch_bounds__(256) void k_red(
    const float* __restrict__ partial, const float* __restrict__ efb,
    const int* __restrict__ order, const int* __restrict__ off,
    const int* __restrict__ counts, const float* __restrict__ best_w,
    float* __restrict__ out) {
  const int slot = blockIdx.x * 256 + threadIdx.x;
  if (slot >= off[4]) return;
  int e = 0;
#pragma unroll
  for (int i = 1; i < 4; i++) if (slot >= off[i]) e = i;
  if (slot - off[e] >= counts[e]) return;
  const int s = order[slot];
  const float bw = best_w[s];
  const int o0 = blockIdx.y * 4;
#pragma unroll
  for (int j = 0; j < 4; j++) {
    const int o = o0 + j;
    float sum = 0.f;
#pragma unroll
    for (int ks = 0; ks < 16; ks++)
      sum += partial[(size_t)ks * 147456 + (size_t)o * 1152 + slot];
    out[(size_t)s * 100 + o] = (sum + efb[e * 100 + o]) * bw;
  }
}

// ---------------------------------------------------------------------------
extern "C" void kernel_launch(void* const* d_in, const int* in_sizes, int n_in,
                              void* d_out, int out_size, void* d_ws, size_t ws_size,
                              hipStream_t stream) {
  const float* x   = (const float*)d_in[0];
  const float* gcw = (const float*)d_in[1];
  const float* gcb = (const float*)d_in[2];
  const float* gfw = (const float*)d_in[3];
  const float* gfb = (const float*)d_in[4];
  const float* c1w = (const float*)d_in[5];
  const float* c1b = (const float*)d_in[6];
  const float* c2w = (const float*)d_in[7];
  const float* c2b = (const float*)d_in[8];
  const float* efw = (const float*)d_in[9];
  const float* efb = (const float*)d_in[10];
  float* out = (float*)d_out;
  float* ws  = (float*)d_ws;

  // ws layout (float-element offsets)
  float*  g_mean   = ws;                        // 16384
  float*  best_w   = ws + 16384;                // 1024
  int*    best_idx = (int*)(ws + 17408);        // 1024
  int*    counts   = (int*)(ws + 18432);        // 4
  int*    cnt2     = (int*)(ws + 18436);        // 4
  int*    off      = (int*)(ws + 18440);        // 5
  int*    order    = (int*)(ws + 18448);        // 1152
  ushort* wp       = (ushort*)(ws + 20480);     // 294912 us  = 147456 f
  ushort* wfc      = (ushort*)(ws + 167936);    // 4194304 us = 2097152 f
  ushort* h1       = (ushort*)(ws + 2265088);   // 16777216 us = 8388608 f
  ushort* h2q      = (ushort*)(ws + 10653696);  // 8388608 us = 4194304 f -> ends 14848000
  float*  partial  = ws + 14848000;             // 16*128*1152 = 2359296 f -> ends 17207296

  float* probs = out + 102400;
  float* aux   = out + 106496;

  hipMemsetAsync(counts, 0, 8 * sizeof(int), stream);  // counts + cnt2

  k_wprep<<<1152, 256, 0, stream>>>(c2w, wp);
  k_wfc<<<16384, 256, 0, stream>>>(efw, wfc);
  k_gate<<<1024, 256, 0, stream>>>(x, gcw, gcb, g_mean);
  k_router<<<4, 256, 0, stream>>>(g_mean, gfw, gfb, probs, best_w, best_idx, counts);
  k_offsets<<<1, 64, 0, stream>>>(counts, off);
  k_scatter<<<4, 256, 0, stream>>>(best_idx, off, cnt2, order);
  k_aux<<<1, 256, 0, stream>>>(probs, aux);
  k_conv1<<<1024, 256, 0, stream>>>(x, c1w, c1b, best_idx, h1);
  k_conv2<<<4096, 256, 0, stream>>>(h1, wp, c2b, best_idx, h2q);
  dim3 g5(36, 16);
  k_fc<<<g5, 256, 0, stream>>>(h2q, wfc, order, off, counts, partial);
  dim3 g6(5, 25);
  k_red<<<g6, 256, 0, stream>>>(partial, efb, order, off, counts, best_w, out);
}

// Round 15
// 252.093 us; speedup vs baseline: 1.0955x; 1.0955x over previous
//
#include <hip/hip_runtime.h>
#include <hip/hip_bf16.h>
#include <cstdint>

// ---------------------------------------------------------------------------
// MoE CNN, hard top-1 dispatch. Round 15: conv1 -> bf16 MFMA implicit GEMM
// (per-strip im2col in LDS, K = 3ci x 9tap padded to 32; fused pool; writes
// conv2's h1 layout directly). conv2/fc/red as R14.
// Sizes: B=1024, Cin=3, HW=32, GC=16, E=4, C1=64, C2=128, FC_IN=8192, NC=100
// Output: [final 1024*100][probs 1024*4][aux 1]
// ---------------------------------------------------------------------------

#define B_TOT 1024

typedef __attribute__((ext_vector_type(8))) short short8;
typedef __attribute__((ext_vector_type(16))) float f32x16;

__device__ __forceinline__ ushort f2bf(float f) {
  uint32_t u = __float_as_uint(f);
  u += 0x7fffu + ((u >> 16) & 1u);  // round-to-nearest-even
  return (ushort)(u >> 16);
}

// ------- K0: w2 fp32 [e][cout][ci][3][3] -> bf16 [e][kk][kb 8][cout 128][8] -
__global__ __launch_bounds__(256) void k_wprep(const float* __restrict__ w2,
                                               ushort* __restrict__ wp) {
  const int i = blockIdx.x * 256 + threadIdx.x;  // 294912 total
  const int j = i & 7;
  const int cout = (i >> 3) & 127;
  const int kb = (i >> 10) & 7;
  const int kkE = i >> 13;          // e*9 + kk
  const int kk = kkE - (kkE / 9) * 9;
  const int e = kkE / 9;
  const int ci = kb * 8 + j;
  const float f = w2[(size_t)(((e * 128 + cout) * 64 + ci) * 9) + kk];
  wp[i] = f2bf(f);
}

// ------- K0c: w1 fp32 [e][64][3][3][3] -> bf16 wA [e][kb 4][cout 64][8] ----
// K index k = kb*8+j = ci*9 + tap for k<27, zero-padded to 32.
__global__ __launch_bounds__(256) void k_w1prep(const float* __restrict__ w1,
                                                ushort* __restrict__ wA) {
  const int i = blockIdx.x * 256 + threadIdx.x;  // 32768 total
  const int j = i & 7;
  const int cout = (i >> 3) & 63;
  const int kb = (i >> 9) & 3;
  const int e = i >> 11;
  const int k = kb * 8 + j;
  float f = 0.f;
  if (k < 27) {
    const int ci = k / 9;
    const int kk = k - ci * 9;
    f = w1[(size_t)(((e * 64 + cout) * 3 + ci) * 9) + kk];
  }
  wA[i] = f2bf(f);
}

// ---------------- K0b: efw fp32 [e][100][8192] -> bf16 [e][kb][cout128][8] -
__global__ __launch_bounds__(256) void k_wfc(const float* __restrict__ efw,
                                             ushort* __restrict__ wfc) {
  const int i = blockIdx.x * 256 + threadIdx.x;  // 4194304 total
  const int j = i & 7;
  const int cout = (i >> 3) & 127;
  const int kb = (i >> 10) & 1023;
  const int e = i >> 20;
  const int k = kb * 8 + j;
  float f = 0.f;
  if (cout < 100) f = efw[((size_t)(e * 100 + cout)) * 8192 + k];
  wfc[i] = f2bf(f);
}

// ---------------- K1: gate conv(3->16)+relu+gap, LDS halo, maskless --------
__global__ __launch_bounds__(256, 2) void k_gate(
    const float* __restrict__ x, const float* __restrict__ gcw,
    const float* __restrict__ gcb, float* __restrict__ g_mean) {
  __shared__ float xs[3 * 34 * 34];  // 13872 B zero-padded halo
  __shared__ float red[4 * 16];
  const int b = blockIdx.x;
  const int t = threadIdx.x;
  const float* xb = x + (size_t)b * 3072;

  for (int c = t; c < 3468; c += 256) {
    const int ci = c / 1156;
    const int rem = c - ci * 1156;
    const int y = rem / 34;
    const int xx = rem - y * 34;
    const int gy = y - 1, gx = xx - 1;
    float v = 0.f;
    if (gy >= 0 && gy < 32 && gx >= 0 && gx < 32) v = xb[ci * 1024 + gy * 32 + gx];
    xs[c] = v;
  }
  __syncthreads();

  const int r = t >> 3;        // output row 0..31
  const int c0 = (t & 7) * 4;  // output col base

  float accp[16][4];
#pragma unroll
  for (int c = 0; c < 16; c++)
#pragma unroll
    for (int p = 0; p < 4; p++) accp[c][p] = 0.f;

#pragma unroll
  for (int ci = 0; ci < 3; ci++) {
    float pv[3][6];
#pragma unroll
    for (int dy = 0; dy < 3; dy++) {
      const float* row = xs + ci * 1156 + (r + dy) * 34 + c0;
#pragma unroll
      for (int dx = 0; dx < 6; dx++) pv[dy][dx] = row[dx];
    }
#pragma unroll
    for (int c = 0; c < 16; c++) {
      const float* wr = gcw + (c * 3 + ci) * 9;
#pragma unroll
      for (int ky = 0; ky < 3; ky++)
#pragma unroll
        for (int kx = 0; kx < 3; kx++) {
          const float wv = wr[ky * 3 + kx];
#pragma unroll
          for (int p = 0; p < 4; p++)
            accp[c][p] += wv * pv[ky][kx + p];
        }
    }
  }

  float sums[16];
#pragma unroll
  for (int c = 0; c < 16; c++) {
    const float bb = gcb[c];
    float s = 0.f;
#pragma unroll
    for (int p = 0; p < 4; p++) s += fmaxf(accp[c][p] + bb, 0.f);
    sums[c] = s;
  }

  const int wave = t >> 6, lane = t & 63;
#pragma unroll
  for (int c = 0; c < 16; c++) {
    float v = sums[c];
    for (int o = 32; o > 0; o >>= 1) v += __shfl_down(v, o);
    if (lane == 0) red[wave * 16 + c] = v;
  }
  __syncthreads();
  if (t < 16) {
    g_mean[b * 16 + t] =
        (red[t] + red[16 + t] + red[32 + t] + red[48 + t]) * (1.f / 1024.f);
  }
}

// ---------------- K2: router linear+softmax, argmax, counts ----------------
__global__ __launch_bounds__(256) void k_router(
    const float* __restrict__ g_mean, const float* __restrict__ gfw,
    const float* __restrict__ gfb, float* __restrict__ probs,
    float* __restrict__ best_w, int* __restrict__ best_idx,
    int* __restrict__ counts) {
  const int b = blockIdx.x * 256 + threadIdx.x;
  float g[16];
#pragma unroll
  for (int c = 0; c < 16; c++) g[c] = g_mean[b * 16 + c];
  float lg[4];
#pragma unroll
  for (int e = 0; e < 4; e++) {
    float s = gfb[e];
#pragma unroll
    for (int c = 0; c < 16; c++) s += g[c] * gfw[e * 16 + c];
    lg[e] = s;
  }
  float m = fmaxf(fmaxf(lg[0], lg[1]), fmaxf(lg[2], lg[3]));
  float ex[4], s = 0.f;
#pragma unroll
  for (int e = 0; e < 4; e++) { ex[e] = expf(lg[e] - m); s += ex[e]; }
  const float inv = 1.f / s;
  float p[4];
#pragma unroll
  for (int e = 0; e < 4; e++) { p[e] = ex[e] * inv; probs[b * 4 + e] = p[e]; }
  int bi = 0; float bp = p[0];
#pragma unroll
  for (int e = 1; e < 4; e++) if (p[e] > bp) { bp = p[e]; bi = e; }
  best_w[b] = bp;
  best_idx[b] = bi;
  atomicAdd(&counts[bi], 1);
}

// ---------------- K2c: 32-aligned segment offsets --------------------------
__global__ void k_offsets(const int* __restrict__ counts, int* __restrict__ off) {
  if (threadIdx.x == 0) {
    int o = 0;
    for (int e = 0; e < 4; e++) { off[e] = o; o += ((counts[e] + 31) & ~31); }
    off[4] = o;
  }
}

// ---------------- K2d: scatter sample ids grouped by expert ----------------
__global__ __launch_bounds__(256) void k_scatter(
    const int* __restrict__ best_idx, const int* __restrict__ off,
    int* __restrict__ cnt2, int* __restrict__ order) {
  const int b = blockIdx.x * 256 + threadIdx.x;
  const int e = best_idx[b];
  const int slot = off[e] + atomicAdd(&cnt2[e], 1);
  order[slot] = b;
}

// ---------------- K3: aux loss ---------------------------------------------
__global__ __launch_bounds__(256) void k_aux(const float* __restrict__ probs,
                                             float* __restrict__ aux_out) {
  __shared__ float red[16];
  const int t = threadIdx.x;
  const int wave = t >> 6, lane = t & 63;
  float sums[4] = {0.f, 0.f, 0.f, 0.f};
  for (int b = t; b < B_TOT; b += 256) {
#pragma unroll
    for (int e = 0; e < 4; e++) sums[e] += probs[b * 4 + e];
  }
#pragma unroll
  for (int e = 0; e < 4; e++) {
    float v = sums[e];
    for (int o = 32; o > 0; o >>= 1) v += __shfl_down(v, o);
    if (lane == 0) red[wave * 4 + e] = v;
  }
  __syncthreads();
  if (t == 0) {
    float aux = 0.f;
#pragma unroll
    for (int e = 0; e < 4; e++) {
      const float mp = (red[e] + red[4 + e] + red[8 + e] + red[12 + e]) * (1.f / 1024.f);
      const float d = mp - 0.25f;
      aux += d * d;
    }
    aux_out[0] = aux * 0.25f;
  }
}

// ---------------- K4: conv1 via bf16 MFMA implicit GEMM --------------------
// Grid 4096 = sample x 4 strips (8 pre-pool rows). Block 256.
// LDS: bf16 halo [3ci][10r][34c] + im2col B[pos 256][Kpad 32].
// Wave wv: m-tile g=wv&1 (cout g*32..+31), n-half nh=wv>>1 (tiles nh*4..+3).
// Fused 2x2 pool -> h1 [b][cig 8][pos 256][8] (conv2's layout).
__global__ __launch_bounds__(256) void k_conv1(
    const float* __restrict__ x, const ushort* __restrict__ wA,
    const float* __restrict__ b1, const int* __restrict__ best_idx,
    ushort* __restrict__ h1q) {
  __shared__ ushort xs[1020];                    // [ci 3][hr 10][hc 34] bf16
  __shared__ __align__(16) ushort Bl[256 * 32];  // [pos][Kpad] 16 KB
  const int blk = blockIdx.x;
  const int b = blk >> 2;
  const int q = blk & 3;  // strip: pre-pool rows 8q..8q+7
  const int t = threadIdx.x;
  const int e = __builtin_amdgcn_readfirstlane(best_idx[b]);
  const float* xb = x + (size_t)b * 3072;
  const float* b1e = b1 + (size_t)e * 64;

  // stage bf16 halo: rows 8q-1..8q+8, cols -1..32, zero-padded
  for (int c = t; c < 1020; c += 256) {
    const int ci = c / 340;
    const int rem = c - ci * 340;
    const int hr = rem / 34;
    const int hc = rem - hr * 34;
    const int gr = 8 * q + hr - 1, gc = hc - 1;
    float v = 0.f;
    if (gr >= 0 && gr < 32 && gc >= 0 && gc < 32) v = xb[ci * 1024 + gr * 32 + gc];
    xs[c] = f2bf(v);
  }
  __syncthreads();

  // im2col: thread = position (rr = t>>5 in strip, cc = t&31)
  {
    const int rr = t >> 5, cc = t & 31;
    ushort us[32];
#pragma unroll
    for (int k = 0; k < 32; k++) {
      ushort v = 0;
      if (k < 27) {
        const int ci = k / 9;
        const int tap = k - ci * 9;
        const int dy = tap / 3, dx = tap - dy * 3;
        v = xs[ci * 340 + (rr + dy) * 34 + cc + dx];
      }
      us[k] = v;
    }
    uint4 pk[2];
    uint* pu = (uint*)pk;
#pragma unroll
    for (int w = 0; w < 8; w++)
      pu[w] = (uint)us[w * 2] | ((uint)us[w * 2 + 1] << 16);
    *(uint4*)(Bl + t * 32) = pk[0];
    *(uint4*)(Bl + t * 32 + 8) = pk[1];
    // second half of K (k 16..31)
    uint4 pk2[2];
    uint* pu2 = (uint*)pk2;
#pragma unroll
    for (int w = 0; w < 8; w++)
      pu2[w] = (uint)us[16 + w * 2] | ((uint)us[16 + w * 2 + 1] << 16);
    *(uint4*)(Bl + t * 32 + 16) = pk2[0];
    *(uint4*)(Bl + t * 32 + 24) = pk2[1];
  }
  __syncthreads();

  const int lane = t & 63;
  const int wv = t >> 6;
  const int g = wv & 1;    // cout tile: g*32
  const int nh = wv >> 1;  // n-tiles nh*4 .. nh*4+3
  const int ln = lane & 31;
  const int half = lane >> 5;

  // A fragments (lane-contiguous): wA[e][kb = s*2+half][g*32+ln][8]
  const short8 af0 = *(const short8*)(wA + (size_t)(((e * 4 + half) * 64) + g * 32 + ln) * 8);
  const short8 af1 = *(const short8*)(wA + (size_t)(((e * 4 + 2 + half) * 64) + g * 32 + ln) * 8);

  f32x16 acc[4];
#pragma unroll
  for (int tt = 0; tt < 4; tt++)
#pragma unroll
    for (int i = 0; i < 16; i++) acc[tt][i] = 0.f;

#pragma unroll
  for (int tt = 0; tt < 4; tt++) {
    const ushort* bcol = Bl + (size_t)((nh * 4 + tt) * 32 + ln) * 32;
    const short8 b0 = *(const short8*)(bcol + half * 8);
    const short8 b1v = *(const short8*)(bcol + 16 + half * 8);
    acc[tt] = __builtin_amdgcn_mfma_f32_32x32x16_bf16(af0, b0, acc[tt], 0, 0, 0);
    acc[tt] = __builtin_amdgcn_mfma_f32_32x32x16_bf16(af1, b1v, acc[tt], 0, 0, 0);
  }

  // biases (wave-uniform per r): cout = g*32 + (r&3) + 8*(r>>2) + 4*half
  float bias[16];
#pragma unroll
  for (int r = 0; r < 16; r++)
    bias[r] = b1e[g * 32 + (r & 3) + 8 * (r >> 2) + 4 * half];

  // fused 2x2 pool: tiles 2j,2j+1 are pre-pool rows; cols via shfl_xor(1).
  // store: h1[b][cig = g*4+rg][pos = (4q + nh*2 + j)*16 + pc][4*half + i]
  const int pc = ln >> 1;
#pragma unroll
  for (int j = 0; j < 2; j++) {
    float pw[16];
#pragma unroll
    for (int r = 0; r < 16; r++) {
      float v = fmaxf(acc[2 * j][r], acc[2 * j + 1][r]);
      v = fmaxf(v, __shfl_xor(v, 1));
      pw[r] = fmaxf(v + bias[r], 0.f);
    }
    if ((lane & 1) == 0) {
      const int pos = (4 * q + nh * 2 + j) * 16 + pc;
      ushort* dst = h1q + (size_t)b * 16384 + pos * 8 + 4 * half;
#pragma unroll
      for (int rg = 0; rg < 4; rg++) {
        uint2 pk;
        pk.x = (uint)f2bf(pw[rg * 4 + 0]) | ((uint)f2bf(pw[rg * 4 + 1]) << 16);
        pk.y = (uint)f2bf(pw[rg * 4 + 2]) | ((uint)f2bf(pw[rg * 4 + 3]) << 16);
        *(uint2*)(dst + (g * 4 + rg) * 2048) = pk;
      }
    }
  }
}

// ---------------- K4b: conv2 bf16 MFMA, 64 couts x 32 spatial per wave -----
__global__ __launch_bounds__(256) void k_conv2(
    const ushort* __restrict__ h1q, const ushort* __restrict__ wp,
    const float* __restrict__ b2, const int* __restrict__ best_idx,
    ushort* __restrict__ h2q) {
  __shared__ uint4 st[864];   // [row 6][cig 8][col 18] x 16B (8 ci bf16)
  __shared__ float pl[2048];  // [cout 128][pooled 16]
  const int blk = blockIdx.x;
  const int b = blk >> 2;
  const int yq = blk & 3;  // out rows yq*4 .. yq*4+3
  const int t = threadIdx.x;
  const int e = __builtin_amdgcn_readfirstlane(best_idx[b]);

  for (int c = t; c < 864; c += 256) {
    const int row = c / 144;           // 8*18
    const int rem = c - row * 144;
    const int cig = rem / 18;
    const int col = rem - cig * 18;
    const int gy = yq * 4 - 1 + row;
    uint4 v = make_uint4(0u, 0u, 0u, 0u);
    if (gy >= 0 && gy < 16 && col >= 1 && col <= 16)
      v = *(const uint4*)(h1q + (size_t)b * 16384 + cig * 2048 +
                          (gy * 16 + col - 1) * 8);
    st[c] = v;  // c == (row*8+cig)*18+col
  }
  __syncthreads();

  const int wv = t >> 6;
  const int g = wv & 1;       // cout group: g*64
  const int h = wv >> 1;      // strip half: pre-pool rows 2h, 2h+1
  const int lane = t & 63;
  const int n = lane & 31;
  const int half = lane >> 5; // k-half
  const int drow = n >> 4;
  const int col = n & 15;
  const int cm0 = g * 64;

  f32x16 acc0, acc1;
#pragma unroll
  for (int i = 0; i < 16; i++) { acc0[i] = 0.f; acc1[i] = 0.f; }

  const ushort* wpe = wp + (size_t)e * 73728;
  const short* sb = (const short*)st;

  for (int kk = 0; kk < 9; kk++) {
    const int ky = kk / 3;
    const int kx = kk - ky * 3;
#pragma unroll
    for (int c4 = 0; c4 < 4; c4++) {
      const int cig = c4 * 2 + half;  // = kb
      const short8 af0 = *(const short8*)(wpe + kk * 8192 +
                                          (size_t)(cig * 128 + cm0 + n) * 8);
      const short8 af1 = *(const short8*)(wpe + kk * 8192 +
                                          (size_t)(cig * 128 + cm0 + 32 + n) * 8);
      const short8 bf = *(const short8*)(sb +
          (((2 * h + drow + ky) * 8 + cig) * 18 + col + kx) * 8);
      acc0 = __builtin_amdgcn_mfma_f32_32x32x16_bf16(af0, bf, acc0, 0, 0, 0);
      acc1 = __builtin_amdgcn_mfma_f32_32x32x16_bf16(af1, bf, acc1, 0, 0, 0);
    }
  }

#pragma unroll
  for (int s = 0; s < 2; s++) {
    const f32x16 a = s ? acc1 : acc0;
#pragma unroll
    for (int r = 0; r < 16; r++) {
      float v = a[r];
      v = fmaxf(v, __shfl_xor(v, 1));
      v = fmaxf(v, __shfl_xor(v, 16));
      if ((lane & 17) == 0) {  // col even, drow==0
        const int rowm = (r & 3) + 8 * (r >> 2) + 4 * half;
        const int pc = (n >> 1) & 7;  // pooled col 0..7
        pl[(cm0 + s * 32 + rowm) * 16 + h * 8 + pc] = v;
      }
    }
  }
  __syncthreads();

  {
    const int coutL = t >> 1;
    const int hh = t & 1;
    const float bias = b2[e * 128 + coutL];
    const float* src = pl + coutL * 16 + hh * 8;
    union { ushort us[8]; uint4 u4; } pk;
#pragma unroll
    for (int j = 0; j < 8; j++) pk.us[j] = f2bf(fmaxf(src[j] + bias, 0.f));
    *(uint4*)(h2q + (size_t)b * 8192 + coutL * 64 + yq * 16 + hh * 8) = pk.u4;
  }
}

// ---------------- K5: FC bf16 MFMA, split-K=16, partial stores (no atomics) -
__global__ __launch_bounds__(256) void k_fc(
    const ushort* __restrict__ h2q, const ushort* __restrict__ wfc,
    const int* __restrict__ order, const int* __restrict__ off,
    const int* __restrict__ counts, float* __restrict__ partial) {
  __shared__ ushort bs[32 * 32 * 8];  // 16 KB
  __shared__ int sid[32];
  const int tix = blockIdx.x;
  const int ks = blockIdx.y;  // K-slice of 512
  const int base = tix * 32;
  if (base >= off[4]) return;
  int e = 0;
#pragma unroll
  for (int i = 1; i < 4; i++) if (base >= off[i]) e = i;
  const int vend = off[e] + counts[e];
  const int t = threadIdx.x;
  if (t < 32) {
    const int pos = base + t;
    sid[t] = (pos < vend) ? order[pos] : -1;
  }
  __syncthreads();

  const int lane = t & 63;
  const int wv = t >> 6;
  const int half = lane >> 5;
  const int mn = lane & 31;
  const int cout0 = wv * 32;
  const int ss = t & 31;
  const int kgrp = t >> 5;
  const int srow = sid[ss] >= 0 ? sid[ss] : 0;
  const ushort* arow = h2q + (size_t)srow * 8192;

  f32x16 acc;
#pragma unroll
  for (int i = 0; i < 16; i++) acc[i] = 0.f;

  const ushort* wbase = wfc + ((size_t)e * 1024 + (size_t)ks * 64) * 1024;
  const short* sb = (const short*)bs;

#pragma unroll
  for (int ch = 0; ch < 2; ch++) {
    const int k0g = ks * 512 + ch * 256;
    if (ch) __syncthreads();
#pragma unroll
    for (int p = 0; p < 4; p++) {
      const int kb = p * 8 + kgrp;
      const uint4 v = *(const uint4*)(arow + k0g + kb * 8);
      *(uint4*)(bs + (kb * 32 + ss) * 8) = v;
    }
    __syncthreads();
#pragma unroll
    for (int kk = 0; kk < 16; kk++) {
      const int kbl = kk * 2 + half;
      const short8 af = *(const short8*)(wbase +
          ((size_t)(ch * 32 + kbl) * 128 + cout0 + mn) * 8);
      const short8 bf = *(const short8*)(sb + (kbl * 32 + mn) * 8);
      acc = __builtin_amdgcn_mfma_f32_32x32x16_bf16(af, bf, acc, 0, 0, 0);
    }
  }

  float* pks = partial + (size_t)ks * 147456;  // 128*1152
#pragma unroll
  for (int r = 0; r < 16; r++) {
    const int cout = cout0 + (r & 3) + 8 * (r >> 2) + 4 * half;
    pks[(size_t)cout * 1152 + base + mn] = acc[r];
  }
}

// ---------------- K5b: reduce 16 K-slices, +bias, *best_w, write out ------
__global__ __launch_bounds__(256) void k_red(
    const float* __restrict__ partial, const float* __restrict__ efb,
    const int* __restrict__ order, const int* __restrict__ off,
    const int* __restrict__ counts, const float* __restrict__ best_w,
    float* __restrict__ out) {
  const int slot = blockIdx.x * 256 + threadIdx.x;
  if (slot >= off[4]) return;
  int e = 0;
#pragma unroll
  for (int i = 1; i < 4; i++) if (slot >= off[i]) e = i;
  if (slot - off[e] >= counts[e]) return;
  const int s = order[slot];
  const float bw = best_w[s];
  const int o0 = blockIdx.y * 4;
#pragma unroll
  for (int j = 0; j < 4; j++) {
    const int o = o0 + j;
    float sum = 0.f;
#pragma unroll
    for (int ks = 0; ks < 16; ks++)
      sum += partial[(size_t)ks * 147456 + (size_t)o * 1152 + slot];
    out[(size_t)s * 100 + o] = (sum + efb[e * 100 + o]) * bw;
  }
}

// ---------------------------------------------------------------------------
extern "C" void kernel_launch(void* const* d_in, const int* in_sizes, int n_in,
                              void* d_out, int out_size, void* d_ws, size_t ws_size,
                              hipStream_t stream) {
  const float* x   = (const float*)d_in[0];
  const float* gcw = (const float*)d_in[1];
  const float* gcb = (const float*)d_in[2];
  const float* gfw = (const float*)d_in[3];
  const float* gfb = (const float*)d_in[4];
  const float* c1w = (const float*)d_in[5];
  const float* c1b = (const float*)d_in[6];
  const float* c2w = (const float*)d_in[7];
  const float* c2b = (const float*)d_in[8];
  const float* efw = (const float*)d_in[9];
  const float* efb = (const float*)d_in[10];
  float* out = (float*)d_out;
  float* ws  = (float*)d_ws;

  // ws layout (float-element offsets)
  float*  g_mean   = ws;                        // 16384
  float*  best_w   = ws + 16384;                // 1024
  int*    best_idx = (int*)(ws + 17408);        // 1024
  int*    counts   = (int*)(ws + 18432);        // 4
  int*    cnt2     = (int*)(ws + 18436);        // 4
  int*    off      = (int*)(ws + 18440);        // 5
  int*    order    = (int*)(ws + 18448);        // 1152
  ushort* wp       = (ushort*)(ws + 20480);     // 294912 us  = 147456 f
  ushort* wfc      = (ushort*)(ws + 167936);    // 4194304 us = 2097152 f
  ushort* h1       = (ushort*)(ws + 2265088);   // 16777216 us = 8388608 f
  ushort* h2q      = (ushort*)(ws + 10653696);  // 8388608 us = 4194304 f -> ends 14848000
  float*  partial  = ws + 14848000;             // 2359296 f -> ends 17207296
  ushort* wA       = (ushort*)(ws + 17207296);  // 32768 us = 16384 f -> ends 17223680

  float* probs = out + 102400;
  float* aux   = out + 106496;

  hipMemsetAsync(counts, 0, 8 * sizeof(int), stream);  // counts + cnt2

  k_wprep<<<1152, 256, 0, stream>>>(c2w, wp);
  k_w1prep<<<128, 256, 0, stream>>>(c1w, wA);
  k_wfc<<<16384, 256, 0, stream>>>(efw, wfc);
  k_gate<<<1024, 256, 0, stream>>>(x, gcw, gcb, g_mean);
  k_router<<<4, 256, 0, stream>>>(g_mean, gfw, gfb, probs, best_w, best_idx, counts);
  k_offsets<<<1, 64, 0, stream>>>(counts, off);
  k_scatter<<<4, 256, 0, stream>>>(best_idx, off, cnt2, order);
  k_aux<<<1, 256, 0, stream>>>(probs, aux);
  k_conv1<<<4096, 256, 0, stream>>>(x, wA, c1b, best_idx, h1);
  k_conv2<<<4096, 256, 0, stream>>>(h1, wp, c2b, best_idx, h2q);
  dim3 g5(36, 16);
  k_fc<<<g5, 256, 0, stream>>>(h2q, wfc, order, off, counts, partial);
  dim3 g6(5, 25);
  k_red<<<g6, 256, 0, stream>>>(partial, efb, order, off, counts, best_w, out);
}